// Round 5
// baseline (149.568 us; speedup 1.0000x reference)
//
#include <hip/hip_runtime.h>
#include <hip/hip_bf16.h>

// VQ-VAE vector quantizer, MI355X gfx950 — round 5.
// K1 prep:   W fp32 -> bf16 (ws) + ||w||^2 + zero accumulators
// K2 gemm:   ksplit=2 scores argmin -> (pd,pi)[2][32768] + z2[32768]
//            (64 rows/wave, 4 rowsets share each B LDS read; no in-loop barriers)
// K3 gather: merge halves, z_q = W[idx] write (LDS transpose), loss from
//            z2 + best_dist (no z re-read: sum(z-q)^2 = sum z^2 + dist).

#define DIM      256
#define NCODES   1024
#define SPB      1024
#define ZQ_ELEMS 8388608
#define NROWS    32768

typedef float f32x4  __attribute__((ext_vector_type(4)));
typedef float f32x2  __attribute__((ext_vector_type(2)));
typedef short bf16x8 __attribute__((ext_vector_type(8)));
typedef short bf16x4 __attribute__((ext_vector_type(4)));

__device__ __forceinline__ short f2bf(float f) {
    union { float f; unsigned u; } v; v.f = f;
    unsigned r = v.u + 0x7FFFu + ((v.u >> 16) & 1u);   // RNE
    return (short)(r >> 16);
}

#define GLL16(g, l)                                                            \
    __builtin_amdgcn_global_load_lds(                                          \
        (const __attribute__((address_space(1))) void*)(g),                    \
        (__attribute__((address_space(3))) void*)(l), 16, 0, 0)

// ---------------- K1: prep ----------------
__global__ __launch_bounds__(256) void prep(const float* __restrict__ w,
                                            short* __restrict__ wbf,
                                            float* __restrict__ wn,
                                            float* __restrict__ acc,
                                            unsigned* __restrict__ done) {
    const int t = threadIdx.x, wv = t >> 6, l = t & 63;
    const int k = blockIdx.x * 4 + wv;          // one wave per code
    const float* wr = w + (size_t)k * DIM + 4 * l;
    f32x4 v = *(const f32x4*)wr;
    bf16x4 p;
    p[0] = f2bf(v[0]); p[1] = f2bf(v[1]); p[2] = f2bf(v[2]); p[3] = f2bf(v[3]);
    *(bf16x4*)(wbf + (size_t)k * DIM + 4 * l) = p;
    float s = v[0]*v[0] + v[1]*v[1] + v[2]*v[2] + v[3]*v[3];
#pragma unroll
    for (int off = 32; off; off >>= 1) s += __shfl_down(s, off);
    if (l == 0) wn[k] = s;
    if (blockIdx.x == 0 && t == 0) { *acc = 0.f; *done = 0u; }
}

// ---------------- K2: gemm + argmin (ksplit=2) ----------------
// grid 1024 x 64 (1 wave). block = 64 z-rows x 512 codes (half h).
// LDS: wb0 [0,16384) unions zs [0,16896); wb1 [16896,33280); wnl separate.
__global__ __launch_bounds__(64) void vq_gemm(const float* __restrict__ z,
                                              const short* __restrict__ wbf,
                                              const float* __restrict__ wn,
                                              float* __restrict__ pd,
                                              int* __restrict__ pi,
                                              float* __restrict__ z2) {
    __shared__ __align__(16) char smem[33280];
    __shared__ float wnl[512];

    const int l   = threadIdx.x;
    const int n16 = l & 15;
    const int q   = l >> 4;
    const int rb  = (int)blockIdx.x >> 1;
    const int h   = (int)blockIdx.x & 1;
    const int n0  = rb * 64;
    const int batch = n0 >> 10, sbase = n0 & 1023;
    const float* zb = z + (size_t)batch * (DIM * SPB) + sbase;
    const short* wh = wbf + ((size_t)h << 9) * DIM;

    // staging offsets for one 32-code tile (16 instrs x 64 lanes x 16B),
    // granule-XOR swizzle within 128B windows (R4-verified, 0 conflicts)
    int soff[16];
#pragma unroll
    for (int i = 0; i < 16; ++i) {
        int G = i * 64 + l, n = G >> 5, p = G & 31;
        soff[i] = n * 256 + 8 * (p ^ (n & 7));
    }
    // kick tile 0 into wb1 (does not overlap zs)
#pragma unroll
    for (int i = 0; i < 16; ++i)
        GLL16(wh + soff[i], smem + 16896 + (i * 64 + l) * 16);

#pragma unroll
    for (int i = 0; i < 8; ++i) wnl[l + 64 * i] = wn[(h << 9) + l + 64 * i];

    // ---- A transpose (coalesced 256B global reads) + z2 partials ----
    float* zs = (float*)smem;                 // [64 c][stride 66]
    const int sx = l & 15, c0 = l >> 4;
    bf16x8 af[4][8];
    f32x4 z2p = {0.f, 0.f, 0.f, 0.f};
    for (int cc = 0; cc < 4; ++cc) {
        __syncthreads();
#pragma unroll
        for (int g = 0; g < 16; ++g) {
            int c = 64 * cc + c0 + 4 * g;
            f32x4 v = *(const f32x4*)(zb + (size_t)c * SPB + 4 * sx);
            float* dst = &zs[(c & 63) * 66 + 4 * sx];
            *(f32x2*)dst       = (f32x2){v[0], v[1]};
            *(f32x2*)(dst + 2) = (f32x2){v[2], v[3]};
            z2p += v * v;
        }
        __syncthreads();
#pragma unroll
        for (int u = 0; u < 2; ++u) {
            int T = 2 * cc + u;
#pragma unroll
            for (int set = 0; set < 4; ++set) {
                bf16x8 a;
#pragma unroll
                for (int j = 0; j < 8; ++j)
                    a[j] = f2bf(zs[(32 * u + 8 * q + j) * 66 + 16 * set + n16]);
                af[set][T] = a;
            }
        }
    }
    // z2: reduce over the 4 c0-groups (lanes xor 16, 32); lanes 0..15 hold
    // s = 4*sx..4*sx+3. Only half h==0 writes.
#pragma unroll
    for (int m = 16; m < 64; m <<= 1) {
        f32x4 o;
#pragma unroll
        for (int e = 0; e < 4; ++e) o[e] = __shfl_xor(z2p[e], m);
        z2p += o;
    }
    if (h == 0 && l < 16) *(f32x4*)(z2 + n0 + 4 * l) = z2p;

    int offT[8];
#pragma unroll
    for (int T = 0; T < 8; ++T) offT[T] = ((4 * T + q) ^ (n16 & 7)) * 16;

    float best[4][4];
    int   bidx[4][4];
#pragma unroll
    for (int s = 0; s < 4; ++s)
#pragma unroll
        for (int r = 0; r < 4; ++r) { best[s][r] = 3.4e38f; bidx[s][r] = 0; }

    __syncthreads();   // fence: all zs reads drained before wb0 is DMA'd

    for (int kt = 0; kt < 16; ++kt) {
        const char* rbuf = smem + ((kt & 1) ? 0 : 16896);
        __builtin_amdgcn_s_waitcnt(0x0070);   // drain DMA that filled rbuf
        if (kt != 15) {
            const short* gb = wh + (size_t)(kt + 1) * 32 * DIM;
            char* db = smem + ((kt & 1) ? 16896 : 0);
#pragma unroll
            for (int i = 0; i < 16; ++i)
                GLL16(gb + soff[i], db + (i * 64 + l) * 16);
        }

        f32x4 ac[4][2];
#pragma unroll
        for (int s = 0; s < 4; ++s) {
            ac[s][0] = (f32x4){0.f, 0.f, 0.f, 0.f};
            ac[s][1] = (f32x4){0.f, 0.f, 0.f, 0.f};
        }
#pragma unroll
        for (int T = 0; T < 8; ++T) {
            bf16x8 b0 = *(const bf16x8*)(rbuf + (n16)      * 512 + offT[T]);
            bf16x8 b1 = *(const bf16x8*)(rbuf + (16 + n16) * 512 + offT[T]);
#pragma unroll
            for (int s = 0; s < 4; ++s) {
                ac[s][0] = __builtin_amdgcn_mfma_f32_16x16x32_bf16(af[s][T], b0, ac[s][0], 0, 0, 0);
                ac[s][1] = __builtin_amdgcn_mfma_f32_16x16x32_bf16(af[s][T], b1, ac[s][1], 0, 0, 0);
            }
        }

        const int   k0 = kt * 32 + n16;
        const float w0 = wnl[k0], w1 = wnl[k0 + 16];
#pragma unroll
        for (int s = 0; s < 4; ++s)
#pragma unroll
            for (int r = 0; r < 4; ++r) {
                float d0 = w0 - 2.f * ac[s][0][r];
                if (d0 < best[s][r]) { best[s][r] = d0; bidx[s][r] = k0; }
                float d1 = w1 - 2.f * ac[s][1][r];
                if (d1 < best[s][r]) { best[s][r] = d1; bidx[s][r] = k0 + 16; }
            }
    }

    // ---- cross-lane argmin over 16 code lanes (low-index tie-break) ----
#pragma unroll
    for (int s = 0; s < 4; ++s)
#pragma unroll
        for (int r = 0; r < 4; ++r) {
            float bv = best[s][r];
            int   bi = bidx[s][r];
#pragma unroll
            for (int m = 1; m < 16; m <<= 1) {
                float ov = __shfl_xor(bv, m);
                int   oi = __shfl_xor(bi, m);
                if (ov < bv || (ov == bv && oi < bi)) { bv = ov; bi = oi; }
            }
            if (n16 == 0) {
                int row = (h << 15) + n0 + 16 * s + 4 * q + r;
                pd[row] = bv;
                pi[row] = bi + (h << 9);
            }
        }
}

// ---------------- K3: merge + gather + write + loss ----------------
// grid 512 x 256. HBM: 32 MB z_q write only (loss needs no z re-read).
__global__ __launch_bounds__(256) void vq_gather(const float* __restrict__ w,
                                                 const float* __restrict__ pd,
                                                 const int* __restrict__ pi,
                                                 const float* __restrict__ z2,
                                                 float* __restrict__ out,
                                                 float* __restrict__ acc,
                                                 unsigned* __restrict__ done) {
    __shared__ __align__(16) float zql[64 * 256];
    __shared__ int ridx[64];

    const int t  = threadIdx.x;
    const int wv = t >> 6;
    const int l  = t & 63;
    const int n0    = blockIdx.x * 64;
    const int batch = n0 >> 10, sbase = n0 & 1023;
    float* ob = out + (size_t)batch * (DIM * SPB) + sbase;

    // merge the two halves + loss contribution (rows of this block)
    float lpart = 0.f;
    if (t < 64) {
        float d0 = pd[n0 + t], d1 = pd[NROWS + n0 + t];
        int   i0 = pi[n0 + t], i1 = pi[NROWS + n0 + t];
        int   ks = (d1 < d0) ? i1 : i0;       // tie -> half 0 (lower idx)
        float dm = (d1 < d0) ? d1 : d0;
        ridx[t]  = ks;
        lpart = z2[n0 + t] + dm;              // = sum_d (z-q)^2 for this row
    }
    __syncthreads();

    // DMA-gather selected code rows (1 KB each), rotated by s granules
    for (int s = 16 * wv; s < 16 * wv + 16; ++s) {
        int ks = ridx[s];
        const float* src = w + (size_t)ks * DIM + 4 * ((l - s) & 63);
        GLL16(src, (char*)zql + s * 1024 + l * 16);
    }
    __builtin_amdgcn_s_waitcnt(0x0070);
    __syncthreads();

    // transposed read: w_row[s][c] at phys dword (c + 4s) & 255
    const int x  = t & 15;     // s-group: s = 4x + r
    const int cg = t >> 4;     // 16 channel groups
#pragma unroll 4
    for (int i = 0; i < 16; ++i) {
        int c = cg + 16 * i;
        f32x4 qv;
#pragma unroll
        for (int r = 0; r < 4; ++r) {
            int s = 4 * x + r;
            qv[r] = zql[s * 256 + ((c + 4 * s) & 255)];
        }
        *(f32x4*)(ob + (size_t)c * SPB + 4 * x) = qv;
    }

    // loss: lpart lives on wave 0 only
    if (wv == 0) {
#pragma unroll
        for (int off = 32; off; off >>= 1) lpart += __shfl_down(lpart, off);
        if (l == 0) {
            atomicAdd(acc, lpart);
            __threadfence();
            unsigned prev = atomicAdd(done, 1u);
            if (prev == 512 - 1) {
                float v = atomicAdd(acc, 0.f) * (1.f / 8388608.f);
                out[ZQ_ELEMS]     = v;
                out[ZQ_ELEMS + 1] = v;
            }
        }
    }
}

extern "C" void kernel_launch(void* const* d_in, const int* in_sizes, int n_in,
                              void* d_out, int out_size, void* d_ws, size_t ws_size,
                              hipStream_t stream) {
    const float* z = (const float*)d_in[0];
    const float* w = (const float*)d_in[1];
    float* out = (float*)d_out;

    char* ws = (char*)d_ws;
    short*    wbf  = (short*)ws;                   // [0, 524288)
    float*    wn   = (float*)(ws + 524288);        // 4 KB
    float*    acc  = (float*)(ws + 528384);
    unsigned* done = (unsigned*)(ws + 528388);
    float*    pd   = (float*)(ws + 532480);        // 2 x 32768 f32
    int*      pi   = (int*)(ws + 794624);          // 2 x 32768 i32
    float*    z2   = (float*)(ws + 1056768);       // 32768 f32

    prep<<<256, 256, 0, stream>>>(w, wbf, wn, acc, done);
    vq_gemm<<<1024, 64, 0, stream>>>(z, wbf, wn, pd, pi, z2);
    vq_gather<<<512, 256, 0, stream>>>(w, pd, pi, z2, out, acc, done);
}